// Round 3
// baseline (633.220 us; speedup 1.0000x reference)
//
#include <hip/hip_runtime.h>
#include <math.h>

typedef long long ll;

// ---------------------------------------------------------------------------
// Job-table fp32 GEMM: up to 4 independent GEMMs per launch.
// C[bz](MxN) = alpha*A.B [+Ci] [+Ci^T] [+Ci2] [+=C]
// A[bz*aB + i*aI + k*aK] (aK==1 or aI==1), B[bz*bB + k*bK + j*bJ] (bJ==1 or bK==1)
// C row-major stride N. M,N multiples of 64, K multiple of 16.
// flags: 1=+Ci[i,j]  2=+Ci[j,i] (square, stride N)  4=+Ci2[i,j]  8=C+=v
// 128 threads, 64x64 tile, 8x4 acc (0.75 B/FLOP LDS -> ~92 TF ceiling).
// ---------------------------------------------------------------------------
struct Job {
    const float *A, *B, *Ci, *Ci2;
    float* C;
    ll aB, bB, ciB, ci2B, cB;
    int aI, aK, bK, bJ;
    int N, K, tpb, tilesN, flags;
    float alpha;
};
struct JobPack { Job j[4]; };

__global__ __launch_bounds__(128) void mgemm_k(JobPack jp, int c0, int c1, int c2)
{
    int bid = blockIdx.x;
    int ji, local;
    if (bid < c0)      { ji = 0; local = bid; }
    else if (bid < c1) { ji = 1; local = bid - c0; }
    else if (bid < c2) { ji = 2; local = bid - c1; }
    else               { ji = 3; local = bid - c2; }
    Job j = jp.j[ji];
    int bz = local / j.tpb;
    int t  = local - bz * j.tpb;
    int ti = t / j.tilesN;
    int tj = t - ti * j.tilesN;
    const float* A = j.A + (ll)bz * j.aB;
    const float* B = j.B + (ll)bz * j.bB;
    float* C = j.C + (ll)bz * j.cB;
    int i0 = ti * 64, j0 = tj * 64;
    __shared__ float As[16][68], Bs[16][68];
    int tid = threadIdx.x;
    int rg = tid >> 4, tx = tid & 15;
    float acc[8][4] = {};

    for (int k0 = 0; k0 < j.K; k0 += 16) {
        if (j.aK == 1) {
            #pragma unroll
            for (int s = 0; s < 2; ++s) {
                int idx = s * 128 + tid;
                int f = idx >> 2, kq = idx & 3;
                float4 v = *(const float4*)(A + (ll)(i0 + f) * j.aI + k0 + kq * 4);
                As[kq*4+0][f] = v.x; As[kq*4+1][f] = v.y;
                As[kq*4+2][f] = v.z; As[kq*4+3][f] = v.w;
            }
        } else {
            #pragma unroll
            for (int s = 0; s < 2; ++s) {
                int idx = s * 128 + tid;
                int kk = idx >> 4, iq = idx & 15;
                *(float4*)&As[kk][iq*4] =
                    *(const float4*)(A + (ll)(k0 + kk) * j.aK + i0 + iq * 4);
            }
        }
        if (j.bJ == 1) {
            #pragma unroll
            for (int s = 0; s < 2; ++s) {
                int idx = s * 128 + tid;
                int kk = idx >> 4, jq = idx & 15;
                *(float4*)&Bs[kk][jq*4] =
                    *(const float4*)(B + (ll)(k0 + kk) * j.bK + j0 + jq * 4);
            }
        } else {
            #pragma unroll
            for (int s = 0; s < 2; ++s) {
                int idx = s * 128 + tid;
                int f = idx >> 2, kq = idx & 3;
                float4 v = *(const float4*)(B + (ll)(j0 + f) * j.bJ + k0 + kq * 4);
                Bs[kq*4+0][f] = v.x; Bs[kq*4+1][f] = v.y;
                Bs[kq*4+2][f] = v.z; Bs[kq*4+3][f] = v.w;
            }
        }
        __syncthreads();
        #pragma unroll
        for (int kk = 0; kk < 16; ++kk) {
            float4 a0 = *(float4*)&As[kk][rg*8];
            float4 a1 = *(float4*)&As[kk][rg*8+4];
            float4 b4 = *(float4*)&Bs[kk][tx*4];
            float a[8] = {a0.x,a0.y,a0.z,a0.w,a1.x,a1.y,a1.z,a1.w};
            float bb[4] = {b4.x,b4.y,b4.z,b4.w};
            #pragma unroll
            for (int m = 0; m < 8; ++m)
                #pragma unroll
                for (int n = 0; n < 4; ++n)
                    acc[m][n] = fmaf(a[m], bb[n], acc[m][n]);
        }
        __syncthreads();
    }

    const float* Ci  = j.Ci  ? j.Ci  + (ll)bz * j.ciB  : nullptr;
    const float* Ci2 = j.Ci2 ? j.Ci2 + (ll)bz * j.ci2B : nullptr;
    #pragma unroll
    for (int m = 0; m < 8; ++m) {
        int gi = i0 + rg * 8 + m;
        ll ro = (ll)gi * j.N + j0 + tx * 4;
        float v[4];
        #pragma unroll
        for (int n = 0; n < 4; ++n) v[n] = j.alpha * acc[m][n];
        if (j.flags & 1) {
            float4 ci = *(const float4*)(Ci + ro);
            v[0]+=ci.x; v[1]+=ci.y; v[2]+=ci.z; v[3]+=ci.w;
        }
        if (j.flags & 2) {
            #pragma unroll
            for (int n = 0; n < 4; ++n) v[n] += Ci[(ll)(j0 + tx*4 + n) * j.N + gi];
        }
        if (j.flags & 4) {
            float4 ci = *(const float4*)(Ci2 + ro);
            v[0]+=ci.x; v[1]+=ci.y; v[2]+=ci.z; v[3]+=ci.w;
        }
        if (j.flags & 8) {
            float4 co = *(const float4*)(C + ro);
            v[0]+=co.x; v[1]+=co.y; v[2]+=co.z; v[3]+=co.w;
        }
        float4 o; o.x=v[0]; o.y=v[1]; o.z=v[2]; o.w=v[3];
        *(float4*)(C + ro) = o;
    }
}

// ---------------------------------------------------------------------------
// Gram partials: 64 threads, 8x8 acc (0.5 B/FLOP -> ~138 TF ceiling).
// part[p][b][t] = X[b][i0:+64, kchunk] . X[b][j0:+64, kchunk]^T, k<2047.
// Upper triangle (15 tiles), P=8 chunks of 256. 1920 blocks, XCD-swizzled.
// ---------------------------------------------------------------------------
__global__ __launch_bounds__(64) void gram_part_k(const float* __restrict__ x,
                                                  float* __restrict__ part)
{
    int flat = blockIdx.x;
    int swz = (flat & 7) * 240 + (flat >> 3);
    int b = swz / 120;
    int rr = swz % 120;
    int p = rr / 15, t = rr % 15;
    int ti = 0, rem = t;
    while (rem >= 5 - ti) { rem -= 5 - ti; ++ti; }
    int tj = ti + rem;
    int i0 = ti * 64, j0 = tj * 64;
    const float* X = x + (ll)b * 320 * 2048;
    __shared__ float As[16][68], Bs[16][68];
    int tid = threadIdx.x;
    int ty = tid >> 3, tx = tid & 7;
    float acc[8][8] = {};
    bool diag = (ti == tj);
    float (*Bsel)[68] = diag ? As : Bs;

    for (int it = 0; it < 16; ++it) {
        int k0 = p * 256 + it * 16;
        #pragma unroll
        for (int s = 0; s < 4; ++s) {
            int idx = s * 64 + tid;
            int f = idx >> 2, kq = idx & 3;
            int kg = k0 + kq * 4;
            float4 va = *(const float4*)(X + (ll)(i0 + f) * 2048 + kg);
            if (kg + 3 >= 2047) {
                float* pa = &va.x;
                #pragma unroll
                for (int u = 0; u < 4; ++u) if (kg + u >= 2047) pa[u] = 0.f;
            }
            As[kq*4+0][f] = va.x; As[kq*4+1][f] = va.y;
            As[kq*4+2][f] = va.z; As[kq*4+3][f] = va.w;
        }
        if (!diag) {
            #pragma unroll
            for (int s = 0; s < 4; ++s) {
                int idx = s * 64 + tid;
                int f = idx >> 2, kq = idx & 3;
                int kg = k0 + kq * 4;
                float4 vb = *(const float4*)(X + (ll)(j0 + f) * 2048 + kg);
                if (kg + 3 >= 2047) {
                    float* pb = &vb.x;
                    #pragma unroll
                    for (int u = 0; u < 4; ++u) if (kg + u >= 2047) pb[u] = 0.f;
                }
                Bs[kq*4+0][f] = vb.x; Bs[kq*4+1][f] = vb.y;
                Bs[kq*4+2][f] = vb.z; Bs[kq*4+3][f] = vb.w;
            }
        }
        __syncthreads();
        #pragma unroll
        for (int kk = 0; kk < 16; ++kk) {
            float4 a0 = *(float4*)&As[kk][ty*8];
            float4 a1 = *(float4*)&As[kk][ty*8+4];
            float4 b0 = *(float4*)&Bsel[kk][tx*8];
            float4 b1 = *(float4*)&Bsel[kk][tx*8+4];
            float a[8] = {a0.x,a0.y,a0.z,a0.w,a1.x,a1.y,a1.z,a1.w};
            float bb[8] = {b0.x,b0.y,b0.z,b0.w,b1.x,b1.y,b1.z,b1.w};
            #pragma unroll
            for (int m = 0; m < 8; ++m)
                #pragma unroll
                for (int n = 0; n < 8; ++n)
                    acc[m][n] = fmaf(a[m], bb[n], acc[m][n]);
        }
        __syncthreads();
    }
    float* out = part + (((ll)p * 16 + b) * 15 + t) * 4096;
    #pragma unroll
    for (int m = 0; m < 8; ++m) {
        float4 o0, o1;
        o0.x=acc[m][0]; o0.y=acc[m][1]; o0.z=acc[m][2]; o0.w=acc[m][3];
        o1.x=acc[m][4]; o1.y=acc[m][5]; o1.z=acc[m][6]; o1.w=acc[m][7];
        *(float4*)(out + (ty*8+m)*64 + tx*8)     = o0;
        *(float4*)(out + (ty*8+m)*64 + tx*8 + 4) = o1;
    }
}

// Sum 8 partials per tile, write both triangles of Gx. Grid 240 = 16*15.
__global__ __launch_bounds__(256) void gram_red_k(const float* __restrict__ part,
                                                  float* __restrict__ Gx)
{
    int bt = blockIdx.x;
    int b = bt / 15, t = bt % 15;
    int ti = 0, rem = t;
    while (rem >= 5 - ti) { rem -= 5 - ti; ++ti; }
    int tj = ti + rem;
    int i0 = ti * 64, j0 = tj * 64;
    int tid = threadIdx.x;
    int tx = tid & 15, rg = tid >> 4;
    float* Gb = Gx + (ll)b * 102400;
    #pragma unroll
    for (int m = 0; m < 4; ++m) {
        int r = rg * 4 + m;
        float s[4] = {};
        for (int p = 0; p < 8; ++p) {
            const float* src = part + (((ll)p * 16 + b) * 15 + t) * 4096 + r * 64 + tx * 4;
            float4 v = *(const float4*)src;
            s[0]+=v.x; s[1]+=v.y; s[2]+=v.z; s[3]+=v.w;
        }
        float4 o; o.x=s[0]; o.y=s[1]; o.z=s[2]; o.w=s[3];
        *(float4*)(Gb + (ll)(i0 + r) * 320 + j0 + tx * 4) = o;
        #pragma unroll
        for (int u = 0; u < 4; ++u)
            Gb[(ll)(j0 + tx * 4 + u) * 320 + (i0 + r)] = s[u];
    }
}

// W = blockdiag(I64, emb, I128); rT0[i][c] = (i>=192) ? emb[i-192][c] : 0
__global__ void setup_k(const float* __restrict__ emb, float* __restrict__ W,
                        float* __restrict__ rT0)
{
    int idx = blockIdx.x * 256 + threadIdx.x;
    if (idx < 102400) {
        int i = idx / 320, jj = idx % 320;
        float v = 0.f;
        if (i < 64) v = (i == jj) ? 1.f : 0.f;
        else if (i < 192) v = (jj >= 64 && jj < 192) ? emb[(i-64)*128 + (jj-64)] : 0.f;
        else v = (jj == i) ? 1.f : 0.f;
        W[idx] = v;
    } else if (idx < 102400 + 40960) {
        int r = idx - 102400;
        int i = r >> 7, cc = r & 127;
        rT0[r] = (i >= 192) ? emb[(i-192)*128 + cc] : 0.f;
    }
}

// ---------------------------------------------------------------------------
// Fused logits + softmax. Block: 64 n-rows x 128 cats, K=320, 128 thr, 8x8 acc.
// logits[b][n][c] = sum_f x[b][f][n] * LWT[b][f][c]; pred = softmax rows.
// ---------------------------------------------------------------------------
__global__ __launch_bounds__(128) void logits_sm_k(const float* __restrict__ x,
                                                   const float* __restrict__ LWT,
                                                   float* __restrict__ logits,
                                                   float* __restrict__ pred)
{
    int b = blockIdx.y;
    int i0 = blockIdx.x * 64;
    const float* X  = x + (ll)b * 320 * 2048;
    const float* Lb = LWT + (ll)b * 320 * 128;
    __shared__ float As[16][68];    // [k][n]
    __shared__ float Bs[16][132];   // [k][c]
    int tid = threadIdx.x;
    int ty = tid >> 4, tx = tid & 15;   // ty: n-group 0..7, tx: c-group 0..15
    float acc[8][8] = {};

    for (int k0 = 0; k0 < 320; k0 += 16) {
        #pragma unroll
        for (int s = 0; s < 2; ++s) {
            int idx = s * 128 + tid;
            int kk = idx >> 4, nq = idx & 15;
            *(float4*)&As[kk][nq*4] =
                *(const float4*)(X + (ll)(k0 + kk) * 2048 + i0 + nq * 4);
        }
        #pragma unroll
        for (int s = 0; s < 4; ++s) {
            int idx = s * 128 + tid;
            int kk = idx >> 5, cq = idx & 31;
            *(float4*)&Bs[kk][cq*4] =
                *(const float4*)(Lb + (ll)(k0 + kk) * 128 + cq * 4);
        }
        __syncthreads();
        #pragma unroll
        for (int kk = 0; kk < 16; ++kk) {
            float4 a0 = *(float4*)&As[kk][ty*8];
            float4 a1 = *(float4*)&As[kk][ty*8+4];
            float4 b0 = *(float4*)&Bs[kk][tx*8];
            float4 b1 = *(float4*)&Bs[kk][tx*8+4];
            float a[8] = {a0.x,a0.y,a0.z,a0.w,a1.x,a1.y,a1.z,a1.w};
            float bb[8] = {b0.x,b0.y,b0.z,b0.w,b1.x,b1.y,b1.z,b1.w};
            #pragma unroll
            for (int m = 0; m < 8; ++m)
                #pragma unroll
                for (int n = 0; n < 8; ++n)
                    acc[m][n] = fmaf(a[m], bb[n], acc[m][n]);
        }
        __syncthreads();
    }

    // softmax: row = 16 lanes (same ty) x 8 cols each; shfl_xor within 16-group
    #pragma unroll
    for (int m = 0; m < 8; ++m) {
        int n_glob = i0 + ty * 8 + m;
        ll ro = ((ll)b * 2048 + n_glob) * 128 + tx * 8;
        float mx = acc[m][0];
        #pragma unroll
        for (int n = 1; n < 8; ++n) mx = fmaxf(mx, acc[m][n]);
        #pragma unroll
        for (int off = 8; off; off >>= 1) mx = fmaxf(mx, __shfl_xor(mx, off));
        float e[8], sm = 0.f;
        #pragma unroll
        for (int n = 0; n < 8; ++n) { e[n] = expf(acc[m][n] - mx); sm += e[n]; }
        #pragma unroll
        for (int off = 8; off; off >>= 1) sm += __shfl_xor(sm, off);
        float inv = 1.f / sm;
        float4 l0, l1, p0, p1;
        l0.x=acc[m][0]; l0.y=acc[m][1]; l0.z=acc[m][2]; l0.w=acc[m][3];
        l1.x=acc[m][4]; l1.y=acc[m][5]; l1.z=acc[m][6]; l1.w=acc[m][7];
        p0.x=e[0]*inv; p0.y=e[1]*inv; p0.z=e[2]*inv; p0.w=e[3]*inv;
        p1.x=e[4]*inv; p1.y=e[5]*inv; p1.z=e[6]*inv; p1.w=e[7]*inv;
        *(float4*)(logits + ro)     = l0;
        *(float4*)(logits + ro + 4) = l1;
        *(float4*)(pred + ro)       = p0;
        *(float4*)(pred + ro + 4)   = p1;
    }
}

extern "C" void kernel_launch(void* const* d_in, const int* in_sizes, int n_in,
                              void* d_out, int out_size, void* d_ws, size_t ws_size,
                              hipStream_t stream)
{
    const float* x   = (const float*)d_in[0];  // (16, 320, 2048)
    const float* emb = (const float*)d_in[1];  // (128, 128)
    const float* Wq  = (const float*)d_in[2];
    const float* Wk  = (const float*)d_in[3];
    const float* Wv  = (const float*)d_in[4];
    const float* P   = (const float*)d_in[5];

    float* logits = (float*)d_out;
    float* pred   = logits + (ll)16 * 2048 * 128;

    const ll SZ = 102400, RS = 40960;
    float* ws = (float*)d_ws;
    float* W    = ws; ws += SZ;
    float* Gx   = ws; ws += 16 * SZ;
    float* G    = ws; ws += 16 * SZ;
    float* PV   = ws; ws += 3 * SZ;
    float* KQ   = ws; ws += 3 * SZ;
    float* Xb   = ws; ws += 16 * SZ;
    float* Yb   = ws; ws += 16 * SZ;
    float* Aall = ws; ws += 48 * SZ;
    float* U    = ws; ws += 16 * SZ;
    float* M01  = ws; ws += 16 * SZ;
    float* rT0  = ws; ws += RS;
    // aliases (lifetimes verified):
    float* part = Xb;    // gram partials (7.87M floats <= X..U span), dead before Xb
    float* T1   = M01;   // W*Gx temp, dead before M01 written
    float* rT1  = Gx;    // Gx dead after T1
    float* rTf  = Yb;    // Yb dead after layer-1 U
    float* LWT  = U;     // U dead after layer-1 Gfix
    float* A0 = Aall, *A1 = Aall + 16*SZ, *A2 = Aall + 32*SZ;
    const float c = 1.f / 2047.f;

    auto mk = [](const float* A, ll aB, int aI, int aK,
                 const float* B, ll bB, int bK, int bJ,
                 float* C, ll cB, int M, int N, int K, float alpha, int flags,
                 const float* Ci, ll ciB, const float* Ci2, ll ci2B) {
        Job j;
        j.A=A; j.B=B; j.Ci=Ci; j.Ci2=Ci2; j.C=C;
        j.aB=aB; j.bB=bB; j.ciB=ciB; j.ci2B=ci2B; j.cB=cB;
        j.aI=aI; j.aK=aK; j.bK=bK; j.bJ=bJ; j.N=N; j.K=K;
        j.tilesN = N/64; j.tpb = (M/64)*(N/64); j.flags=flags; j.alpha=alpha;
        return j;
    };
    auto fire = [&](const Job* js, const int* nb, int n) {
        JobPack jp;
        int cum[4], tot = 0;
        for (int i = 0; i < 4; ++i) {
            jp.j[i] = js[i < n ? i : 0];
            tot += (i < n ? nb[i] : 0);
            cum[i] = tot;
        }
        mgemm_k<<<tot, 128, 0, stream>>>(jp, cum[0], cum[1], cum[2]);
    };

    // setup: W + rT0
    setup_k<<<560, 256, 0, stream>>>(emb, W, rT0);
    // Gram
    gram_part_k<<<1920, 64, 0, stream>>>(x, part);
    gram_red_k<<<240, 256, 0, stream>>>(part, Gx);
    // P1: T1 = W*Gx  |  PV = P*Wv  |  KQ = Wk^T*Wq
    {
        Job js[3] = {
            mk(W, 0, 320, 1,   Gx, SZ, 320, 1,  T1, SZ, 320, 320, 320, 1.f, 0, 0, 0, 0, 0),
            mk(P, SZ, 320, 1,  Wv, SZ, 320, 1,  PV, SZ, 320, 320, 320, 1.f, 0, 0, 0, 0, 0),
            mk(Wk, SZ, 1, 320, Wq, SZ, 320, 1,  KQ, SZ, 320, 320, 320, 1.f, 0, 0, 0, 0, 0)};
        int nb[3] = {400, 75, 75};
        fire(js, nb, 3);
    }
    // P2: G = T1*W^T
    {
        Job js[1] = { mk(T1, SZ, 320, 1,  W, 0, 1, 320,  G, SZ, 320, 320, 320, 1.f, 0, 0, 0, 0, 0) };
        int nb[1] = {400};
        fire(js, nb, 1);
    }
    // layers
    for (int l = 0; l < 3; ++l) {
        const float* PVl = PV + (ll)l * SZ;
        const float* KQl = KQ + (ll)l * SZ;
        float* Al = Aall + (ll)l * 16 * SZ;
        if (l < 2) {
            Job js1[2] = {
                mk(PVl, 0, 320, 1,  G, SZ, 320, 1,  Xb, SZ, 320, 320, 320, 1.f, 0, 0, 0, 0, 0),
                mk(KQl, 0, 320, 1,  G, SZ, 320, 1,  Yb, SZ, 320, 320, 320, 1.f, 0, 0, 0, 0, 0)};
            int nb1[2] = {400, 400};
            fire(js1, nb1, 2);
            Job js2[2] = {
                mk(Xb, SZ, 320, 1,  KQl, 0, 320, 1,  Al, SZ, 320, 320, 320, c, 0, 0, 0, 0, 0),
                mk(Xb, SZ, 320, 1,  Yb, SZ, 320, 1,  U,  SZ, 320, 320, 320, c, 0, 0, 0, 0, 0)};
            int nb2[2] = {400, 400};
            fire(js2, nb2, 2);
            Job js3[1] = {
                mk(U, SZ, 320, 1,  Al, SZ, 1, 320,  G, SZ, 320, 320, 320, 1.f, 1|2|8, U, SZ, 0, 0)};
            int nb3[1] = {400};
            fire(js3, nb3, 1);
        } else {
            Job js1[2] = {
                mk(PVl, 0, 320, 1,  G, SZ, 320, 1,  Xb, SZ, 320, 320, 320, 1.f, 0, 0, 0, 0, 0),
                mk(A1, SZ, 320, 1,  A0, SZ, 320, 1, M01, SZ, 320, 320, 320, 1.f, 1|4, A1, SZ, A0, SZ)};
            int nb1[2] = {400, 400};
            fire(js1, nb1, 2);
            Job js2[1] = {
                mk(Xb, SZ, 320, 1,  KQl, 0, 320, 1,  Al, SZ, 320, 320, 320, c, 0, 0, 0, 0, 0)};
            int nb2[1] = {400};
            fire(js2, nb2, 1);
        }
    }
    // rT1 = rT0 + (A2 rows 192:)^T * emb   (M=320, N=128, K=128)
    {
        Job js[1] = {
            mk(A2 + 192*320, SZ, 1, 320,  emb, 0, 128, 1,  rT1, RS, 320, 128, 128, 1.f, 1, rT0, 0, 0, 0)};
        int nb[1] = {160};
        fire(js, nb, 1);
    }
    // rTf = rT1 + M01^T * rT1   (M=320, N=128, K=320)
    {
        Job js[1] = {
            mk(M01, SZ, 1, 320,  rT1, RS, 128, 1,  rTf, RS, 320, 128, 320, 1.f, 1, rT1, RS, 0, 0)};
        int nb[1] = {160};
        fire(js, nb, 1);
    }
    // LWT = W^T * rTf   (M=320, N=128, K=320)
    {
        Job js[1] = {
            mk(W, 0, 1, 320,  rTf, RS, 128, 1,  LWT, RS, 320, 128, 320, 1.f, 0, 0, 0, 0, 0)};
        int nb[1] = {160};
        fire(js, nb, 1);
    }
    // logits + softmax
    logits_sm_k<<<dim3(32, 16), 128, 0, stream>>>(x, LWT, logits, pred);
}

// Round 4
// 462.621 us; speedup vs baseline: 1.3688x; 1.3688x over previous
//
#include <hip/hip_runtime.h>
#include <math.h>

typedef long long ll;

// ---------------------------------------------------------------------------
// Job-table fp32 GEMM, 256 threads, 64x64 tile, 4x4 acc, reg-prefetch +
// double-buffered LDS. Up to 4 independent jobs per launch.
// C[bz](MxN) = alpha*A.B [+Ci] [+Ci^T] [+=C];  K==0 -> pure copy epilogue.
// A[bz*aB + i*aI + k*aK] (aK==1 or aI==1), B[bz*bB + k*bK + j*bJ] (bJ==1 or bK==1)
// flags: 1=+Ci[i,j] (stride ciI)  2=+Ci[j,i]  8=C+=v
// ---------------------------------------------------------------------------
struct Job {
    const float *A, *B, *Ci;
    float* C;
    ll aB, bB, ciB, cB;
    int aI, aK, bK, bJ;
    int N, K, cI, ciI;
    int tpb, tilesN, flags;
    float alpha;
};
struct JobPack { Job j[4]; };

__global__ __launch_bounds__(256) void mgemm_k(JobPack jp, int c0, int c1, int c2)
{
    int bid = blockIdx.x;
    int ji, local;
    if (bid < c0)      { ji = 0; local = bid; }
    else if (bid < c1) { ji = 1; local = bid - c0; }
    else if (bid < c2) { ji = 2; local = bid - c1; }
    else               { ji = 3; local = bid - c2; }
    Job j = jp.j[ji];
    int bz = local / j.tpb;
    int t  = local - bz * j.tpb;
    int ti = t / j.tilesN, tj = t - ti * j.tilesN;
    const float* A = j.A + (ll)bz * j.aB;
    const float* B = j.B + (ll)bz * j.bB;
    float* C = j.C + (ll)bz * j.cB;
    int i0 = ti * 64, j0 = tj * 64;
    __shared__ float As[2][16][68], Bs[2][16][68];
    int tid = threadIdx.x;
    int tx = tid & 15, ty = tid >> 4;
    float acc[4][4] = {};

    if (j.K > 0) {
        int af = tid >> 2, akq = tid & 3;    // transpose-load path coords
        int akk = tid >> 4, aiq = tid & 15;  // direct path coords
        bool aT = (j.aK == 1);
        bool bT = (j.bJ != 1);
        float4 pa, pb;
        auto ldA = [&](int k0) {
            return aT ? *(const float4*)(A + (ll)(i0 + af) * j.aI + k0 + akq * 4)
                      : *(const float4*)(A + (ll)(k0 + akk) * j.aK + i0 + aiq * 4);
        };
        auto ldB = [&](int k0) {
            return bT ? *(const float4*)(B + (ll)(j0 + af) * j.bJ + k0 + akq * 4)
                      : *(const float4*)(B + (ll)(k0 + akk) * j.bK + j0 + aiq * 4);
        };
        auto stA = [&](int buf, float4 v) {
            if (aT) { As[buf][akq*4+0][af]=v.x; As[buf][akq*4+1][af]=v.y;
                      As[buf][akq*4+2][af]=v.z; As[buf][akq*4+3][af]=v.w; }
            else *(float4*)&As[buf][akk][aiq*4] = v;
        };
        auto stB = [&](int buf, float4 v) {
            if (bT) { Bs[buf][akq*4+0][af]=v.x; Bs[buf][akq*4+1][af]=v.y;
                      Bs[buf][akq*4+2][af]=v.z; Bs[buf][akq*4+3][af]=v.w; }
            else *(float4*)&Bs[buf][akk][aiq*4] = v;
        };
        pa = ldA(0); pb = ldB(0);
        stA(0, pa); stB(0, pb);
        __syncthreads();
        int nk = j.K >> 4;
        for (int it = 0; it < nk; ++it) {
            int cur = it & 1;
            bool more = (it + 1 < nk);
            if (more) { pa = ldA((it + 1) << 4); pb = ldB((it + 1) << 4); }
            #pragma unroll
            for (int kk = 0; kk < 16; ++kk) {
                float4 a4 = *(float4*)&As[cur][kk][ty * 4];
                float4 b4 = *(float4*)&Bs[cur][kk][tx * 4];
                float a[4] = {a4.x, a4.y, a4.z, a4.w};
                float bb[4] = {b4.x, b4.y, b4.z, b4.w};
                #pragma unroll
                for (int m = 0; m < 4; ++m)
                    #pragma unroll
                    for (int n = 0; n < 4; ++n)
                        acc[m][n] = fmaf(a[m], bb[n], acc[m][n]);
            }
            if (more) { stA(cur ^ 1, pa); stB(cur ^ 1, pb); __syncthreads(); }
        }
    }

    const float* Ci = j.Ci + (ll)bz * j.ciB;
    #pragma unroll
    for (int m = 0; m < 4; ++m) {
        int gi = i0 + ty * 4 + m;
        int col = j0 + tx * 4;
        ll ro = (ll)gi * j.cI + col;
        float v[4];
        #pragma unroll
        for (int n = 0; n < 4; ++n) v[n] = j.alpha * acc[m][n];
        if (j.flags & 1) {
            float4 ci = *(const float4*)(Ci + (ll)gi * j.ciI + col);
            v[0]+=ci.x; v[1]+=ci.y; v[2]+=ci.z; v[3]+=ci.w;
        }
        if (j.flags & 2) {
            #pragma unroll
            for (int n = 0; n < 4; ++n) v[n] += Ci[(ll)(col + n) * j.ciI + gi];
        }
        if (j.flags & 8) {
            float4 co = *(const float4*)(C + ro);
            v[0]+=co.x; v[1]+=co.y; v[2]+=co.z; v[3]+=co.w;
        }
        float4 o; o.x=v[0]; o.y=v[1]; o.z=v[2]; o.w=v[3];
        *(float4*)(C + ro) = o;
    }
}

// ---------------------------------------------------------------------------
// Gram partials: 128 thr, 64x64 tile, 8x4 acc, reg-prefetch + LDS dbuf.
// part[p][b][t] = X[b][i0:+64, chunk_p] . X[b][j0:+64, chunk_p]^T, k<2047.
// Upper triangle (15 tiles), P=6 chunks of 352. 1440 blocks, XCD-swizzled.
// ---------------------------------------------------------------------------
__global__ __launch_bounds__(128) void gram_part_k(const float* __restrict__ x,
                                                   float* __restrict__ part)
{
    int flat = blockIdx.x;                      // 0..1439
    int swz = (flat & 7) * 180 + (flat >> 3);
    int b = swz / 90;
    int rr = swz % 90;
    int p = rr / 15, t = rr % 15;
    int ti = 0, rem = t;
    while (rem >= 5 - ti) { rem -= 5 - ti; ++ti; }
    int tj = ti + rem;
    int i0 = ti * 64, j0 = tj * 64;
    const float* X = x + (ll)b * 320 * 2048;
    __shared__ float As[2][16][68], Bs[2][16][68];
    int tid = threadIdx.x;
    int rg = tid >> 4, tx = tid & 15;
    bool diag = (ti == tj);
    float acc[8][4] = {};
    int kbase = p * 352;
    const int NIT = 22;
    float4 va[2], vb[2];

    auto ldT = [&](const float* base, int k0, float4* v) {
        #pragma unroll
        for (int s = 0; s < 2; ++s) {
            int idx = s * 128 + tid;
            int f = idx >> 2, kq = idx & 3;
            int kg = kbase + k0 + kq * 4;
            int kc = kg <= 2044 ? kg : 2044;      // clamp addr, mask values
            float4 w = *(const float4*)(base + (ll)f * 2048 + kc);
            if (kg + 3 >= 2047) {
                if (kg + 0 >= 2047) w.x = 0.f;
                if (kg + 1 >= 2047) w.y = 0.f;
                if (kg + 2 >= 2047) w.z = 0.f;
                if (kg + 3 >= 2047) w.w = 0.f;
            }
            v[s] = w;
        }
    };
    auto stT = [&](float (*S)[68], float4* v) {
        #pragma unroll
        for (int s = 0; s < 2; ++s) {
            int idx = s * 128 + tid;
            int f = idx >> 2, kq = idx & 3;
            S[kq*4+0][f]=v[s].x; S[kq*4+1][f]=v[s].y;
            S[kq*4+2][f]=v[s].z; S[kq*4+3][f]=v[s].w;
        }
    };

    ldT(X + (ll)i0 * 2048, 0, va);
    if (!diag) ldT(X + (ll)j0 * 2048, 0, vb);
    stT(As[0], va); if (!diag) stT(Bs[0], vb);
    __syncthreads();
    for (int it = 0; it < NIT; ++it) {
        int cur = it & 1;
        bool more = (it + 1 < NIT);
        if (more) {
            ldT(X + (ll)i0 * 2048, (it + 1) * 16, va);
            if (!diag) ldT(X + (ll)j0 * 2048, (it + 1) * 16, vb);
        }
        float (*Bsel)[68] = diag ? As[cur] : Bs[cur];
        #pragma unroll
        for (int kk = 0; kk < 16; ++kk) {
            float4 a0 = *(float4*)&As[cur][kk][rg * 8];
            float4 a1 = *(float4*)&As[cur][kk][rg * 8 + 4];
            float4 b4 = *(float4*)&Bsel[kk][tx * 4];
            float a[8] = {a0.x,a0.y,a0.z,a0.w,a1.x,a1.y,a1.z,a1.w};
            float bb[4] = {b4.x,b4.y,b4.z,b4.w};
            #pragma unroll
            for (int m = 0; m < 8; ++m)
                #pragma unroll
                for (int n = 0; n < 4; ++n)
                    acc[m][n] = fmaf(a[m], bb[n], acc[m][n]);
        }
        if (more) { stT(As[cur ^ 1], va); if (!diag) stT(Bs[cur ^ 1], vb); __syncthreads(); }
    }
    float* out = part + (((ll)p * 16 + b) * 15 + t) * 4096;
    #pragma unroll
    for (int m = 0; m < 8; ++m) {
        float4 o; o.x=acc[m][0]; o.y=acc[m][1]; o.z=acc[m][2]; o.w=acc[m][3];
        *(float4*)(out + (rg * 8 + m) * 64 + tx * 4) = o;
    }
}

// Sum 6 partials, write both triangles of Gx; also copy top/bot rows into T1
// (T1 = W*Gx has identity rows outside the middle 64:192 band). Grid 240.
__global__ __launch_bounds__(256) void gram_red_k(const float* __restrict__ part,
                                                  float* __restrict__ Gx,
                                                  float* __restrict__ T1)
{
    int bt = blockIdx.x;
    int b = bt / 15, t = bt % 15;
    int ti = 0, rem = t;
    while (rem >= 5 - ti) { rem -= 5 - ti; ++ti; }
    int tj = ti + rem;
    int i0 = ti * 64, j0 = tj * 64;
    int tid = threadIdx.x;
    int tx = tid & 15, rg = tid >> 4;
    float* Gb = Gx + (ll)b * 102400;
    float* Tb = T1 + (ll)b * 102400;
    bool wi = (ti == 0 || ti >= 3);
    bool wj = (tj == 0 || tj >= 3);
    #pragma unroll
    for (int m = 0; m < 4; ++m) {
        int r = rg * 4 + m;
        float s[4] = {};
        for (int p = 0; p < 6; ++p) {
            const float* src = part + (((ll)p * 16 + b) * 15 + t) * 4096 + r * 64 + tx * 4;
            float4 v = *(const float4*)src;
            s[0]+=v.x; s[1]+=v.y; s[2]+=v.z; s[3]+=v.w;
        }
        float4 o; o.x=s[0]; o.y=s[1]; o.z=s[2]; o.w=s[3];
        ll rd = (ll)(i0 + r) * 320 + j0 + tx * 4;
        *(float4*)(Gb + rd) = o;
        if (wi) *(float4*)(Tb + rd) = o;
        #pragma unroll
        for (int u = 0; u < 4; ++u) {
            ll rt = (ll)(j0 + tx * 4 + u) * 320 + (i0 + r);
            Gb[rt] = s[u];
            if (wj) Tb[rt] = s[u];
        }
    }
}

// rT0[i][c] = (i>=192) ? emb[i-192][c] : 0    (320 x 128, batch-shared)
__global__ void setup_k(const float* __restrict__ emb, float* __restrict__ rT0)
{
    int idx = blockIdx.x * 256 + threadIdx.x;
    if (idx >= 40960) return;
    int i = idx >> 7, c = idx & 127;
    rT0[idx] = (i >= 192) ? emb[(i - 192) * 128 + c] : 0.f;
}

// ---------------------------------------------------------------------------
// Fused logits + softmax. 256 thr, 64 n-rows x 128 cats, K=320, 8x4 acc,
// reg-prefetch + dbuf. B operand read piecewise: rows [0,64)u[192,320) from
// rT3, rows [64,192) from Mmid = E^T * rT3[64:192]  (i.e. W^T * rT3).
// ---------------------------------------------------------------------------
__global__ __launch_bounds__(256) void logits_sm_k(const float* __restrict__ x,
                                                   const float* __restrict__ rT3,
                                                   const float* __restrict__ Mmid,
                                                   float* __restrict__ logits,
                                                   float* __restrict__ pred)
{
    int b = blockIdx.y;
    int i0 = blockIdx.x * 64;
    const float* X  = x + (ll)b * 320 * 2048;
    const float* Rb = rT3 + (ll)b * 40960;
    const float* Mb = Mmid + (ll)b * 16384;
    __shared__ float As[2][16][68], Bs[2][16][132];
    int tid = threadIdx.x;
    int ty = tid >> 5, tx = tid & 31;
    int akk = tid >> 4, anq = tid & 15;
    float acc[8][4] = {};
    float4 pa, pb0, pb1;

    auto ldA = [&](int k0) {
        return *(const float4*)(X + (ll)(k0 + akk) * 2048 + i0 + anq * 4);
    };
    auto ldB = [&](int k0, int s) {
        int idx = s * 256 + tid;
        int kk = idx >> 5, cq = idx & 31;
        int r = k0 + kk;
        const float* src = (r < 64 || r >= 192) ? Rb + (ll)r * 128 : Mb + (ll)(r - 64) * 128;
        return *(const float4*)(src + cq * 4);
    };
    auto stAB = [&](int buf) {
        *(float4*)&As[buf][akk][anq * 4] = pa;
        { int kk = tid >> 5, cq = tid & 31;        *(float4*)&Bs[buf][kk][cq * 4] = pb0; }
        { int i2 = 256 + tid; int kk = i2 >> 5, cq = i2 & 31; *(float4*)&Bs[buf][kk][cq * 4] = pb1; }
    };

    pa = ldA(0); pb0 = ldB(0, 0); pb1 = ldB(0, 1);
    stAB(0);
    __syncthreads();
    for (int it = 0; it < 20; ++it) {
        int cur = it & 1;
        bool more = (it < 19);
        if (more) { pa = ldA((it+1)*16); pb0 = ldB((it+1)*16, 0); pb1 = ldB((it+1)*16, 1); }
        #pragma unroll
        for (int kk = 0; kk < 16; ++kk) {
            float4 a0 = *(float4*)&As[cur][kk][ty * 8];
            float4 a1 = *(float4*)&As[cur][kk][ty * 8 + 4];
            float4 b4 = *(float4*)&Bs[cur][kk][tx * 4];
            float a[8] = {a0.x,a0.y,a0.z,a0.w,a1.x,a1.y,a1.z,a1.w};
            float bb[4] = {b4.x,b4.y,b4.z,b4.w};
            #pragma unroll
            for (int m = 0; m < 8; ++m)
                #pragma unroll
                for (int n = 0; n < 4; ++n)
                    acc[m][n] = fmaf(a[m], bb[n], acc[m][n]);
        }
        if (more) { stAB(cur ^ 1); __syncthreads(); }
    }

    #pragma unroll
    for (int m = 0; m < 8; ++m) {
        int n_glob = i0 + ty * 8 + m;
        ll ro = ((ll)b * 2048 + n_glob) * 128 + tx * 4;
        float v0 = acc[m][0], v1 = acc[m][1], v2 = acc[m][2], v3 = acc[m][3];
        float mx = fmaxf(fmaxf(v0, v1), fmaxf(v2, v3));
        #pragma unroll
        for (int off = 16; off; off >>= 1) mx = fmaxf(mx, __shfl_xor(mx, off));
        float e0 = expf(v0 - mx), e1 = expf(v1 - mx);
        float e2 = expf(v2 - mx), e3 = expf(v3 - mx);
        float sm = e0 + e1 + e2 + e3;
        #pragma unroll
        for (int off = 16; off; off >>= 1) sm += __shfl_xor(sm, off);
        float inv = 1.f / sm;
        float4 lo; lo.x=v0; lo.y=v1; lo.z=v2; lo.w=v3;
        float4 po; po.x=e0*inv; po.y=e1*inv; po.z=e2*inv; po.w=e3*inv;
        *(float4*)(logits + ro) = lo;
        *(float4*)(pred + ro) = po;
    }
}

extern "C" void kernel_launch(void* const* d_in, const int* in_sizes, int n_in,
                              void* d_out, int out_size, void* d_ws, size_t ws_size,
                              hipStream_t stream)
{
    const float* x   = (const float*)d_in[0];  // (16, 320, 2048)
    const float* emb = (const float*)d_in[1];  // (128, 128)
    const float* Wq  = (const float*)d_in[2];
    const float* Wk  = (const float*)d_in[3];
    const float* Wv  = (const float*)d_in[4];
    const float* P   = (const float*)d_in[5];

    float* logits = (float*)d_out;
    float* pred   = logits + (ll)16 * 2048 * 128;

    const ll SZ = 102400, RS = 40960;
    float* ws = (float*)d_ws;
    float* Gx   = ws; ws += 16 * SZ;
    float* G    = ws; ws += 16 * SZ;
    float* PV   = ws; ws += 3 * SZ;
    float* KQ   = ws; ws += 3 * SZ;
    float* T1   = ws; ws += 16 * SZ;   // alias: X (layer temp)
    float* Aall = ws; ws += 48 * SZ;
    float* U    = ws; ws += 16 * SZ;
    float* rT0  = ws; ws += RS;
    float* rT1  = ws; ws += 16 * RS;
    float* rT2  = ws; ws += 16 * RS;
    float* rT3  = ws; ws += 16 * RS;
    float* Xb   = T1;                  // T1 dead after Gb launch
    float* part = Aall;                // 6*16*15*4096 = 5.90M <= Aall+U (6.55M)
    float* Mmid = Gx;                  // Gx dead after P1
    float* A0 = Aall, *A1 = Aall + 16*SZ, *A2 = Aall + 32*SZ;
    const float c = 1.f / 2047.f;

    auto mk = [](const float* A, ll aB, int aI, int aK,
                 const float* B, ll bB, int bK, int bJ,
                 float* C, ll cB, int cI,
                 int M, int N, int K, float alpha, int flags,
                 const float* Ci, ll ciB, int ciI) {
        Job j;
        j.A = A; j.B = B; j.C = C;
        j.Ci = Ci ? Ci : (const float*)C;
        j.aB = aB; j.bB = bB; j.ciB = Ci ? ciB : 0; j.cB = cB;
        j.aI = aI; j.aK = aK; j.bK = bK; j.bJ = bJ;
        j.N = N; j.K = K; j.cI = cI; j.ciI = ciI;
        j.tilesN = N / 64; j.tpb = (M / 64) * (N / 64);
        j.flags = flags; j.alpha = alpha;
        return j;
    };
    auto fire = [&](const Job* js, const int* nb, int n) {
        JobPack jp;
        int cum[4], tot = 0;
        for (int i = 0; i < 4; ++i) {
            jp.j[i] = js[i < n ? i : 0];
            tot += (i < n ? nb[i] : 0);
            cum[i] = tot;
        }
        mgemm_k<<<tot, 256, 0, stream>>>(jp, cum[0], cum[1], cum[2]);
    };

    // 1) rT0
    setup_k<<<160, 256, 0, stream>>>(emb, rT0);
    // 2-3) Gram -> Gx (+ T1 top/bot rows)
    gram_part_k<<<1440, 128, 0, stream>>>(x, part);
    gram_red_k<<<240, 256, 0, stream>>>(part, Gx, T1);
    // 4) P1: T1 mid rows = E*Gx[64:192]  |  PV = P*Wv  |  KQ = Wk^T*Wq
    {
        Job js[3] = {
            mk(emb, 0, 128, 1,  Gx + 64*320, SZ, 320, 1,  T1 + 64*320, SZ, 320,
               128, 320, 128, 1.f, 0, 0, 0, 0),
            mk(P,  SZ, 320, 1,  Wv, SZ, 320, 1,  PV, SZ, 320, 320, 320, 320, 1.f, 0, 0, 0, 0),
            mk(Wk, SZ, 1, 320,  Wq, SZ, 320, 1,  KQ, SZ, 320, 320, 320, 320, 1.f, 0, 0, 0, 0)};
        int nb[3] = {160, 75, 75};
        fire(js, nb, 3);
    }
    // 5) Gb: G cols 0:64 & 192:320 = T1 (copy jobs, K=0); G[:,64:192] = T1[:,64:192]*E^T
    {
        Job js[3] = {
            mk(emb, 0, 1, 1,  emb, 0, 1, 1,  G, SZ, 320, 320, 64, 0, 0.f, 1, T1, SZ, 320),
            mk(emb, 0, 1, 1,  emb, 0, 1, 1,  G + 192, SZ, 320, 320, 128, 0, 0.f, 1, T1 + 192, SZ, 320),
            mk(T1 + 64, SZ, 320, 1,  emb, 0, 1, 128,  G + 64, SZ, 320,
               320, 128, 128, 1.f, 0, 0, 0, 0)};
        int nb[3] = {80, 160, 160};
        fire(js, nb, 3);
    }
    // 6..15) layers: X = PV_l*G; A_l = c*X*KQ_l; U = A_l*G; G += U + U^T + U*A_l^T
    for (int l = 0; l < 3; ++l) {
        const float* PVl = PV + (ll)l * SZ;
        const float* KQl = KQ + (ll)l * SZ;
        float* Al = Aall + (ll)l * 16 * SZ;
        {
            Job js[1] = { mk(PVl, 0, 320, 1,  G, SZ, 320, 1,  Xb, SZ, 320,
                             320, 320, 320, 1.f, 0, 0, 0, 0) };
            int nb[1] = {400}; fire(js, nb, 1);
        }
        {
            Job js[1] = { mk(Xb, SZ, 320, 1,  KQl, 0, 320, 1,  Al, SZ, 320,
                             320, 320, 320, c, 0, 0, 0, 0) };
            int nb[1] = {400}; fire(js, nb, 1);
        }
        if (l < 2) {
            {
                Job js[1] = { mk(Al, SZ, 320, 1,  G, SZ, 320, 1,  U, SZ, 320,
                                 320, 320, 320, 1.f, 0, 0, 0, 0) };
                int nb[1] = {400}; fire(js, nb, 1);
            }
            {
                Job js[1] = { mk(U, SZ, 320, 1,  Al, SZ, 1, 320,  G, SZ, 320,
                                 320, 320, 320, 1.f, 1 | 2 | 8, U, SZ, 320) };
                int nb[1] = {400}; fire(js, nb, 1);
            }
        }
    }
    // 16) rT1 = rT0 + A2^T[:,192:] * emb   (K=128)
    {
        Job js[1] = { mk(A2 + 192*320, SZ, 1, 320,  emb, 0, 128, 1,  rT1, RS, 128,
                         320, 128, 128, 1.f, 1, rT0, 0, 128) };
        int nb[1] = {160}; fire(js, nb, 1);
    }
    // 17) rT2 = rT1 + A1^T * rT1
    {
        Job js[1] = { mk(A1, SZ, 1, 320,  rT1, RS, 128, 1,  rT2, RS, 128,
                         320, 128, 320, 1.f, 1, rT1, RS, 128) };
        int nb[1] = {160}; fire(js, nb, 1);
    }
    // 18) rT3 = rT2 + A0^T * rT2
    {
        Job js[1] = { mk(A0, SZ, 1, 320,  rT2, RS, 128, 1,  rT3, RS, 128,
                         320, 128, 320, 1.f, 1, rT2, RS, 128) };
        int nb[1] = {160}; fire(js, nb, 1);
    }
    // 19) Mmid = E^T * rT3[64:192]
    {
        Job js[1] = { mk(emb, 0, 1, 128,  rT3 + 64*128, RS, 128, 1,  Mmid, 16384, 128,
                         128, 128, 128, 1.f, 0, 0, 0, 0) };
        int nb[1] = {64}; fire(js, nb, 1);
    }
    // 20) logits + softmax (piecewise W^T*rT3 read)
    logits_sm_k<<<dim3(32, 16), 256, 0, stream>>>(x, rT3, Mmid, logits, pred);
}

// Round 5
// 452.389 us; speedup vs baseline: 1.3997x; 1.0226x over previous
//
#include <hip/hip_runtime.h>
#include <math.h>

typedef long long ll;
typedef unsigned int uint;
typedef unsigned short ushort;
typedef __attribute__((ext_vector_type(4))) float f32x4;
typedef __attribute__((ext_vector_type(8))) short bf16x8;

// split fp32 -> hi/lo bf16 (RNE both)
__device__ inline void split2(float v, ushort& h, ushort& l)
{
    uint u = __float_as_uint(v);
    uint uh = u + (0x7FFFu + ((u >> 16) & 1u));
    h = (ushort)(uh >> 16);
    float hf = __uint_as_float((uint)h << 16);
    float d = v - hf;
    uint ud = __float_as_uint(d);
    l = (ushort)((ud + (0x7FFFu + ((ud >> 16) & 1u))) >> 16);
}

// ---------------------------------------------------------------------------
// fp32 job-table GEMM (small stages). 256 thr, 64x64 tile, 4x4 acc, dbuf.
// flags: 1=+Ci[i,j]  2=+Ci[j,i]  8=C+=v  16=also write split bf16 planes (Cs)
// ---------------------------------------------------------------------------
struct Job {
    const float *A, *B, *Ci;
    float* C;
    ushort* Cs;
    ll aB, bB, ciB, cB, csLo;
    int aI, aK, bK, bJ;
    int N, K, cI, ciI;
    int tpb, tilesN, flags;
    float alpha;
};
struct JobPack { Job j[4]; };

__global__ __launch_bounds__(256) void mgemm_k(JobPack jp, int c0, int c1, int c2)
{
    int bid = blockIdx.x;
    int ji, local;
    if (bid < c0)      { ji = 0; local = bid; }
    else if (bid < c1) { ji = 1; local = bid - c0; }
    else if (bid < c2) { ji = 2; local = bid - c1; }
    else               { ji = 3; local = bid - c2; }
    Job j = jp.j[ji];
    int bz = local / j.tpb;
    int t  = local - bz * j.tpb;
    int ti = t / j.tilesN, tj = t - ti * j.tilesN;
    const float* A = j.A + (ll)bz * j.aB;
    const float* B = j.B + (ll)bz * j.bB;
    float* C = j.C + (ll)bz * j.cB;
    int i0 = ti * 64, j0 = tj * 64;
    __shared__ float As[2][16][68], Bs[2][16][68];
    int tid = threadIdx.x;
    int tx = tid & 15, ty = tid >> 4;
    float acc[4][4] = {};

    if (j.K > 0) {
        int af = tid >> 2, akq = tid & 3;
        int akk = tid >> 4, aiq = tid & 15;
        bool aT = (j.aK == 1);
        bool bT = (j.bJ != 1);
        float4 pa, pb;
        auto ldA = [&](int k0) {
            return aT ? *(const float4*)(A + (ll)(i0 + af) * j.aI + k0 + akq * 4)
                      : *(const float4*)(A + (ll)(k0 + akk) * j.aK + i0 + aiq * 4);
        };
        auto ldB = [&](int k0) {
            return bT ? *(const float4*)(B + (ll)(j0 + af) * j.bJ + k0 + akq * 4)
                      : *(const float4*)(B + (ll)(k0 + akk) * j.bK + j0 + aiq * 4);
        };
        auto stA = [&](int buf, float4 v) {
            if (aT) { As[buf][akq*4+0][af]=v.x; As[buf][akq*4+1][af]=v.y;
                      As[buf][akq*4+2][af]=v.z; As[buf][akq*4+3][af]=v.w; }
            else *(float4*)&As[buf][akk][aiq*4] = v;
        };
        auto stB = [&](int buf, float4 v) {
            if (bT) { Bs[buf][akq*4+0][af]=v.x; Bs[buf][akq*4+1][af]=v.y;
                      Bs[buf][akq*4+2][af]=v.z; Bs[buf][akq*4+3][af]=v.w; }
            else *(float4*)&Bs[buf][akk][aiq*4] = v;
        };
        pa = ldA(0); pb = ldB(0);
        stA(0, pa); stB(0, pb);
        __syncthreads();
        int nk = j.K >> 4;
        for (int it = 0; it < nk; ++it) {
            int cur = it & 1;
            bool more = (it + 1 < nk);
            if (more) { pa = ldA((it + 1) << 4); pb = ldB((it + 1) << 4); }
            #pragma unroll
            for (int kk = 0; kk < 16; ++kk) {
                float4 a4 = *(float4*)&As[cur][kk][ty * 4];
                float4 b4 = *(float4*)&Bs[cur][kk][tx * 4];
                float a[4] = {a4.x, a4.y, a4.z, a4.w};
                float bb[4] = {b4.x, b4.y, b4.z, b4.w};
                #pragma unroll
                for (int m = 0; m < 4; ++m)
                    #pragma unroll
                    for (int n = 0; n < 4; ++n)
                        acc[m][n] = fmaf(a[m], bb[n], acc[m][n]);
            }
            if (more) { stA(cur ^ 1, pa); stB(cur ^ 1, pb); __syncthreads(); }
        }
    }

    const float* Ci = j.Ci + (ll)bz * j.ciB;
    #pragma unroll
    for (int m = 0; m < 4; ++m) {
        int gi = i0 + ty * 4 + m;
        int col = j0 + tx * 4;
        ll ro = (ll)gi * j.cI + col;
        float v[4];
        #pragma unroll
        for (int n = 0; n < 4; ++n) v[n] = j.alpha * acc[m][n];
        if (j.flags & 1) {
            float4 ci = *(const float4*)(Ci + (ll)gi * j.ciI + col);
            v[0]+=ci.x; v[1]+=ci.y; v[2]+=ci.z; v[3]+=ci.w;
        }
        if (j.flags & 2) {
            #pragma unroll
            for (int n = 0; n < 4; ++n) v[n] += Ci[(ll)(col + n) * j.ciI + gi];
        }
        if (j.flags & 8) {
            float4 co = *(const float4*)(C + ro);
            v[0]+=co.x; v[1]+=co.y; v[2]+=co.z; v[3]+=co.w;
        }
        float4 o; o.x=v[0]; o.y=v[1]; o.z=v[2]; o.w=v[3];
        *(float4*)(C + ro) = o;
        if (j.flags & 16) {
            ushort* cs = j.Cs + (ll)bz * j.cB;
            #pragma unroll
            for (int n = 0; n < 4; ++n) {
                ushort h, l; split2(v[n], h, l);
                cs[(ll)gi * j.cI + col + n] = h;
                cs[(ll)gi * j.cI + col + n + j.csLo] = l;
            }
        }
    }
}

// ---------------------------------------------------------------------------
// MFMA bf16x3 GEMM, fixed 320x320x320 per batch (16), C = alpha*A.B [+Ci fp32]
// A/B are split bf16 planes: hi at ptr, lo at ptr+Lo. B is the TRANSPOSED
// operand layout (row j holds B[:,j], k-contiguous). Grid 400 = 16b x 25 tiles.
// Outputs: optional fp32 C (stride SZ) and/or split planes Cs (+csLo).
// ---------------------------------------------------------------------------
struct MJob {
    const ushort *Ah, *Bh;
    const float* Ci;
    float* C;
    ushort* Cs;
    ll aB, bB, aLo, bLo, csLo;
    float alpha;
    int useCi;
};

__global__ __launch_bounds__(256) void mfma_gemm_k(MJob j)
{
    const ll SZ = 102400;
    int bid = blockIdx.x;
    int swz = (bid & 7) * 50 + (bid >> 3);
    int b = swz / 25, t = swz - b * 25;
    int i0 = (t / 5) * 64, j0 = (t % 5) * 64;
    const ushort* Ah = j.Ah + (ll)b * j.aB;
    const ushort* Bh = j.Bh + (ll)b * j.bB;
    int tid = threadIdx.x;
    int wv = tid >> 6, lane = tid & 63;
    int lr = lane & 15, kb = (lane >> 4) * 8;
    f32x4 hh[4], hl[4], lh[4];
    f32x4 zz = {0.f, 0.f, 0.f, 0.f};
    #pragma unroll
    for (int f = 0; f < 4; ++f) { hh[f] = zz; hl[f] = zz; lh[f] = zz; }
    const ushort* Arow = Ah + (ll)(i0 + wv * 16 + lr) * 320 + kb;
    for (int k0 = 0; k0 < 320; k0 += 32) {
        bf16x8 ah = *(const bf16x8*)(Arow + k0);
        bf16x8 al = *(const bf16x8*)(Arow + j.aLo + k0);
        #pragma unroll
        for (int f = 0; f < 4; ++f) {
            const ushort* Brow = Bh + (ll)(j0 + f * 16 + lr) * 320 + kb + k0;
            bf16x8 bh_ = *(const bf16x8*)(Brow);
            bf16x8 bl_ = *(const bf16x8*)(Brow + j.bLo);
            hh[f] = __builtin_amdgcn_mfma_f32_16x16x32_bf16(ah, bh_, hh[f], 0, 0, 0);
            hl[f] = __builtin_amdgcn_mfma_f32_16x16x32_bf16(ah, bl_, hl[f], 0, 0, 0);
            lh[f] = __builtin_amdgcn_mfma_f32_16x16x32_bf16(al, bh_, lh[f], 0, 0, 0);
        }
    }
    int orow0 = i0 + wv * 16 + (lane >> 4) * 4;
    #pragma unroll
    for (int f = 0; f < 4; ++f) {
        int col = j0 + f * 16 + lr;
        #pragma unroll
        for (int r = 0; r < 4; ++r) {
            ll o = (ll)b * SZ + (ll)(orow0 + r) * 320 + col;
            float v = j.alpha * (hh[f][r] + hl[f][r] + lh[f][r]);
            if (j.useCi) v += j.Ci[o];
            if (j.C) j.C[o] = v;
            if (j.Cs) {
                ushort h, l; split2(v, h, l);
                j.Cs[o] = h; j.Cs[o + j.csLo] = l;
            }
        }
    }
}

// ---------------------------------------------------------------------------
// Gram via MFMA: part[p][b][t] = Xc_tile_i . Xc_tile_j^T over K-chunk p (512),
// k<2047 masked. On-the-fly fp32 -> hi/lo bf16 via LDS. Grid 960 = 4p*16b*15t.
// ---------------------------------------------------------------------------
__global__ __launch_bounds__(256) void gram_mfma_k(const float* __restrict__ x,
                                                   float* __restrict__ part)
{
    int flat = blockIdx.x;
    int swz = (flat & 7) * 120 + (flat >> 3);
    int b = swz / 60;
    int rr = swz - b * 60;
    int p = rr / 15, t = rr - p * 15;
    int ti = 0, rem = t;
    while (rem >= 5 - ti) { rem -= 5 - ti; ++ti; }
    int tj = ti + rem;
    int i0 = ti * 64, j0 = tj * 64;
    bool diag = (ti == tj);
    const float* X = x + (ll)b * 320 * 2048;
    __shared__ __align__(16) ushort Ah[64 * 40], Al_[64 * 40], Bh[64 * 40], Bl_[64 * 40];
    int tid = threadIdx.x;
    int wv = tid >> 6, lane = tid & 63;
    int lr = lane & 15, kb = (lane >> 4) * 8;
    int cr = tid >> 2, ck = (tid & 3) * 8;
    f32x4 hh[4], hl[4], lh[4];
    f32x4 zz = {0.f, 0.f, 0.f, 0.f};
    #pragma unroll
    for (int f = 0; f < 4; ++f) { hh[f] = zz; hl[f] = zz; lh[f] = zz; }
    const ushort* BhS = diag ? Ah : Bh;
    const ushort* BlS = diag ? Al_ : Bl_;

    for (int it = 0; it < 16; ++it) {
        int kg0 = p * 512 + it * 32;
        {
            const float* src = X + (ll)(i0 + cr) * 2048 + kg0 + ck;
            float4 v0 = *(const float4*)src;
            float4 v1 = *(const float4*)(src + 4);
            float vals[8] = {v0.x,v0.y,v0.z,v0.w,v1.x,v1.y,v1.z,v1.w};
            if (kg0 + ck + 7 >= 2047) {
                #pragma unroll
                for (int u = 0; u < 8; ++u) if (kg0 + ck + u >= 2047) vals[u] = 0.f;
            }
            bf16x8 hv, lv;
            #pragma unroll
            for (int u = 0; u < 8; ++u) { ushort h, l; split2(vals[u], h, l);
                                          hv[u] = (short)h; lv[u] = (short)l; }
            *(bf16x8*)&Ah[cr * 40 + ck] = hv;
            *(bf16x8*)&Al_[cr * 40 + ck] = lv;
        }
        if (!diag) {
            const float* src = X + (ll)(j0 + cr) * 2048 + kg0 + ck;
            float4 v0 = *(const float4*)src;
            float4 v1 = *(const float4*)(src + 4);
            float vals[8] = {v0.x,v0.y,v0.z,v0.w,v1.x,v1.y,v1.z,v1.w};
            if (kg0 + ck + 7 >= 2047) {
                #pragma unroll
                for (int u = 0; u < 8; ++u) if (kg0 + ck + u >= 2047) vals[u] = 0.f;
            }
            bf16x8 hv, lv;
            #pragma unroll
            for (int u = 0; u < 8; ++u) { ushort h, l; split2(vals[u], h, l);
                                          hv[u] = (short)h; lv[u] = (short)l; }
            *(bf16x8*)&Bh[cr * 40 + ck] = hv;
            *(bf16x8*)&Bl_[cr * 40 + ck] = lv;
        }
        __syncthreads();
        bf16x8 ah = *(const bf16x8*)&Ah[(wv * 16 + lr) * 40 + kb];
        bf16x8 al = *(const bf16x8*)&Al_[(wv * 16 + lr) * 40 + kb];
        #pragma unroll
        for (int f = 0; f < 4; ++f) {
            bf16x8 bh_ = *(const bf16x8*)&BhS[(f * 16 + lr) * 40 + kb];
            bf16x8 bl_ = *(const bf16x8*)&BlS[(f * 16 + lr) * 40 + kb];
            hh[f] = __builtin_amdgcn_mfma_f32_16x16x32_bf16(ah, bh_, hh[f], 0, 0, 0);
            hl[f] = __builtin_amdgcn_mfma_f32_16x16x32_bf16(ah, bl_, hl[f], 0, 0, 0);
            lh[f] = __builtin_amdgcn_mfma_f32_16x16x32_bf16(al, bh_, lh[f], 0, 0, 0);
        }
        __syncthreads();
    }
    float* out = part + (((ll)p * 16 + b) * 15 + t) * 4096;
    int orow0 = wv * 16 + (lane >> 4) * 4;
    #pragma unroll
    for (int f = 0; f < 4; ++f) {
        int col = f * 16 + lr;
        #pragma unroll
        for (int r = 0; r < 4; ++r)
            out[(orow0 + r) * 64 + col] = hh[f][r] + hl[f][r] + lh[f][r];
    }
}

// Sum 4 partials, write both triangles of Gx; copy identity-band rows into T1.
__global__ __launch_bounds__(256) void gram_red_k(const float* __restrict__ part,
                                                  float* __restrict__ Gx,
                                                  float* __restrict__ T1)
{
    int bt = blockIdx.x;
    int b = bt / 15, t = bt % 15;
    int ti = 0, rem = t;
    while (rem >= 5 - ti) { rem -= 5 - ti; ++ti; }
    int tj = ti + rem;
    int i0 = ti * 64, j0 = tj * 64;
    int tid = threadIdx.x;
    int tx = tid & 15, rg = tid >> 4;
    float* Gb = Gx + (ll)b * 102400;
    float* Tb = T1 + (ll)b * 102400;
    bool wi = (ti == 0 || ti >= 3);
    bool wj = (tj == 0 || tj >= 3);
    #pragma unroll
    for (int m = 0; m < 4; ++m) {
        int r = rg * 4 + m;
        float s[4] = {};
        for (int p = 0; p < 4; ++p) {
            const float* src = part + (((ll)p * 16 + b) * 15 + t) * 4096 + r * 64 + tx * 4;
            float4 v = *(const float4*)src;
            s[0]+=v.x; s[1]+=v.y; s[2]+=v.z; s[3]+=v.w;
        }
        float4 o; o.x=s[0]; o.y=s[1]; o.z=s[2]; o.w=s[3];
        ll rd = (ll)(i0 + r) * 320 + j0 + tx * 4;
        *(float4*)(Gb + rd) = o;
        if (wi) *(float4*)(Tb + rd) = o;
        #pragma unroll
        for (int u = 0; u < 4; ++u) {
            ll rt = (ll)(j0 + tx * 4 + u) * 320 + (i0 + r);
            Gb[rt] = s[u];
            if (wj) Tb[rt] = s[u];
        }
    }
}

// rT0[i][c] = (i>=192) ? emb[i-192][c] : 0
__global__ void setup_k(const float* __restrict__ emb, float* __restrict__ rT0)
{
    int idx = blockIdx.x * 256 + threadIdx.x;
    if (idx >= 40960) return;
    int i = idx >> 7, c = idx & 127;
    rT0[idx] = (i >= 192) ? emb[(i - 192) * 128 + c] : 0.f;
}

// ---------------------------------------------------------------------------
// Fused logits + softmax (fp32), as round 4.
// ---------------------------------------------------------------------------
__global__ __launch_bounds__(256) void logits_sm_k(const float* __restrict__ x,
                                                   const float* __restrict__ rT3,
                                                   const float* __restrict__ Mmid,
                                                   float* __restrict__ logits,
                                                   float* __restrict__ pred)
{
    int b = blockIdx.y;
    int i0 = blockIdx.x * 64;
    const float* X  = x + (ll)b * 320 * 2048;
    const float* Rb = rT3 + (ll)b * 40960;
    const float* Mb = Mmid + (ll)b * 16384;
    __shared__ float As[2][16][68], Bs[2][16][132];
    int tid = threadIdx.x;
    int ty = tid >> 5, tx = tid & 31;
    int akk = tid >> 4, anq = tid & 15;
    float acc[8][4] = {};
    float4 pa, pb0, pb1;

    auto ldA = [&](int k0) {
        return *(const float4*)(X + (ll)(k0 + akk) * 2048 + i0 + anq * 4);
    };
    auto ldB = [&](int k0, int s) {
        int idx = s * 256 + tid;
        int kk = idx >> 5, cq = idx & 31;
        int r = k0 + kk;
        const float* src = (r < 64 || r >= 192) ? Rb + (ll)r * 128 : Mb + (ll)(r - 64) * 128;
        return *(const float4*)(src + cq * 4);
    };
    auto stAB = [&](int buf) {
        *(float4*)&As[buf][akk][anq * 4] = pa;
        { int kk = tid >> 5, cq = tid & 31;        *(float4*)&Bs[buf][kk][cq * 4] = pb0; }
        { int i2 = 256 + tid; int kk = i2 >> 5, cq = i2 & 31; *(float4*)&Bs[buf][kk][cq * 4] = pb1; }
    };

    pa = ldA(0); pb0 = ldB(0, 0); pb1 = ldB(0, 1);
    stAB(0);
    __syncthreads();
    for (int it = 0; it < 20; ++it) {
        int cur = it & 1;
        bool more = (it < 19);
        if (more) { pa = ldA((it+1)*16); pb0 = ldB((it+1)*16, 0); pb1 = ldB((it+1)*16, 1); }
        #pragma unroll
        for (int kk = 0; kk < 16; ++kk) {
            float4 a0 = *(float4*)&As[cur][kk][ty * 8];
            float4 a1 = *(float4*)&As[cur][kk][ty * 8 + 4];
            float4 b4 = *(float4*)&Bs[cur][kk][tx * 4];
            float a[8] = {a0.x,a0.y,a0.z,a0.w,a1.x,a1.y,a1.z,a1.w};
            float bb[4] = {b4.x,b4.y,b4.z,b4.w};
            #pragma unroll
            for (int m = 0; m < 8; ++m)
                #pragma unroll
                for (int n = 0; n < 4; ++n)
                    acc[m][n] = fmaf(a[m], bb[n], acc[m][n]);
        }
        if (more) { stAB(cur ^ 1); __syncthreads(); }
    }

    #pragma unroll
    for (int m = 0; m < 8; ++m) {
        int n_glob = i0 + ty * 8 + m;
        ll ro = ((ll)b * 2048 + n_glob) * 128 + tx * 4;
        float v0 = acc[m][0], v1 = acc[m][1], v2 = acc[m][2], v3 = acc[m][3];
        float mx = fmaxf(fmaxf(v0, v1), fmaxf(v2, v3));
        #pragma unroll
        for (int off = 16; off; off >>= 1) mx = fmaxf(mx, __shfl_xor(mx, off));
        float e0 = expf(v0 - mx), e1 = expf(v1 - mx);
        float e2 = expf(v2 - mx), e3 = expf(v3 - mx);
        float sm = e0 + e1 + e2 + e3;
        #pragma unroll
        for (int off = 16; off; off >>= 1) sm += __shfl_xor(sm, off);
        float inv = 1.f / sm;
        float4 lo; lo.x=v0; lo.y=v1; lo.z=v2; lo.w=v3;
        float4 po; po.x=e0*inv; po.y=e1*inv; po.z=e2*inv; po.w=e3*inv;
        *(float4*)(logits + ro) = lo;
        *(float4*)(pred + ro) = po;
    }
}

extern "C" void kernel_launch(void* const* d_in, const int* in_sizes, int n_in,
                              void* d_out, int out_size, void* d_ws, size_t ws_size,
                              hipStream_t stream)
{
    const float* x   = (const float*)d_in[0];  // (16, 320, 2048)
    const float* emb = (const float*)d_in[1];  // (128, 128)
    const float* Wq  = (const float*)d_in[2];
    const float* Wk  = (const float*)d_in[3];
    const float* Wv  = (const float*)d_in[4];
    const float* P   = (const float*)d_in[5];

    float* logits = (float*)d_out;
    float* pred   = logits + (ll)16 * 2048 * 128;

    const ll SZ = 102400, RS = 40960;
    float* ws = (float*)d_ws;
    float* Gx   = ws; ws += 16 * SZ;   // alias: Xs planes (chain), Mmid (end)
    float* G    = ws; ws += 16 * SZ;
    float* GsF  = ws; ws += 16 * SZ;
    float* PVf  = ws; ws += 3 * SZ;
    float* PVsF = ws; ws += 3 * SZ;
    float* KQf  = ws; ws += 3 * SZ;
    float* KQsF = ws; ws += 3 * SZ;
    float* T1   = ws; ws += 16 * SZ;   // alias: Hf (layers)
    float* HsF  = ws; ws += 16 * SZ;
    float* Aall = ws; ws += 48 * SZ;   // part aliased at front (3.93M < 4.92M)
    float* AsF  = ws; ws += 16 * SZ;
    float* rT0  = ws; ws += RS;
    float* rT1  = ws; ws += 16 * RS;
    float* rT2  = ws; ws += 16 * RS;
    float* rT3  = ws; ws += 16 * RS;

    ushort* Gs   = (ushort*)GsF;
    ushort* PVs  = (ushort*)PVsF;
    ushort* KQTs = (ushort*)KQsF;
    ushort* Hs   = (ushort*)HsF;
    ushort* As   = (ushort*)AsF;
    ushort* Xs   = (ushort*)Gx;
    float*  Hf   = T1;
    float*  part = Aall;
    float*  Mmid = Gx;
    float* A0 = Aall, *A1 = Aall + 16*SZ, *A2 = Aall + 32*SZ;
    const float cinv = 1.f / 2047.f;

    auto mk = [](const float* A, ll aB, int aI, int aK,
                 const float* B, ll bB, int bK, int bJ,
                 float* C, ll cB, int cI,
                 int M, int N, int K, float alpha, int flags,
                 const float* Ci, ll ciB, int ciI,
                 ushort* Cs, ll csLo) {
        Job j;
        j.A = A; j.B = B; j.C = C;
        j.Ci = Ci ? Ci : (const float*)C;
        j.Cs = Cs; j.csLo = csLo;
        j.aB = aB; j.bB = bB; j.ciB = Ci ? ciB : 0; j.cB = cB;
        j.aI = aI; j.aK = aK; j.bK = bK; j.bJ = bJ;
        j.N = N; j.K = K; j.cI = cI; j.ciI = ciI;
        j.tilesN = N / 64; j.tpb = (M / 64) * (N / 64);
        j.flags = flags; j.alpha = alpha;
        return j;
    };
    auto fire = [&](const Job* js, const int* nb, int n) {
        JobPack jp;
        int cum[4], tot = 0;
        for (int i = 0; i < 4; ++i) {
            jp.j[i] = js[i < n ? i : 0];
            tot += (i < n ? nb[i] : 0);
            cum[i] = tot;
        }
        mgemm_k<<<tot, 256, 0, stream>>>(jp, cum[0], cum[1], cum[2]);
    };
    auto mfire = [&](const ushort* Ahp, ll aB, ll aLo,
                     const ushort* Bhp, ll bB, ll bLo,
                     const float* Ci, int useCi,
                     float* C, ushort* Cs, ll csLo, float alpha) {
        MJob m;
        m.Ah = Ahp; m.Bh = Bhp; m.Ci = Ci ? Ci : (const float*)Ahp;
        m.C = C; m.Cs = Cs;
        m.aB = aB; m.bB = bB; m.aLo = aLo; m.bLo = bLo; m.csLo = csLo;
        m.alpha = alpha; m.useCi = useCi;
        mfma_gemm_k<<<400, 256, 0, stream>>>(m);
    };

    // 1) rT0
    setup_k<<<160, 256, 0, stream>>>(emb, rT0);
    // 2-3) Gram (MFMA) -> Gx fp32 (+ T1 identity-band rows)
    gram_mfma_k<<<960, 256, 0, stream>>>(x, part);
    gram_red_k<<<240, 256, 0, stream>>>(part, Gx, T1);
    // 4) P1: T1 mid = E*Gx[64:192] | PV = P*Wv (+split) | KQT = Wq^T*Wk (+split)
    {
        Job js[3] = {
            mk(emb, 0, 128, 1,  Gx + 64*320, SZ, 320, 1,  T1 + 64*320, SZ, 320,
               128, 320, 128, 1.f, 0, 0, 0, 0, 0, 0),
            mk(P,  SZ, 320, 1,  Wv, SZ, 320, 1,  PVf, SZ, 320,
               320, 320, 320, 1.f, 16, 0, 0, 0, PVs, 3*SZ),
            mk(Wq, SZ, 1, 320,  Wk, SZ, 320, 1,  KQf, SZ, 320,
               320, 320, 320, 1.f, 16, 0, 0, 0, KQTs, 3*SZ)};
        int nb[3] = {160, 75, 75};
        fire(js, nb, 3);
    }
    // 5) Gb: G = T1*W^T piecewise, fp32 + split planes
    {
        Job js[3] = {
            mk(emb, 0, 1, 1,  emb, 0, 1, 1,  G, SZ, 320,
               320, 64, 0, 0.f, 1|16, T1, SZ, 320, Gs, 16*SZ),
            mk(emb, 0, 1, 1,  emb, 0, 1, 1,  G + 192, SZ, 320,
               320, 128, 0, 0.f, 1|16, T1 + 192, SZ, 320, Gs + 192, 16*SZ),
            mk(T1 + 64, SZ, 320, 1,  emb, 0, 1, 128,  G + 64, SZ, 320,
               320, 128, 128, 1.f, 16, 0, 0, 0, Gs + 64, 16*SZ)};
        int nb[3] = {80, 160, 160};
        fire(js, nb, 3);
    }
    // 6..15) layers (MFMA bf16x3):
    //   X = PV_l*G; A_l = c*X*KQ_l; H = G + A*G; G = H + H*A^T
    for (int l = 0; l < 3; ++l) {
        const ushort* PVl = PVs + (ll)l * SZ;
        const ushort* KQl = KQTs + (ll)l * SZ;
        float* Afp = Aall + (ll)l * 16 * SZ;
        mfire(PVl, 0, 3*SZ,   Gs, SZ, 16*SZ,  nullptr, 0,
              nullptr, Xs, 16*SZ, 1.f);
        mfire(Xs, SZ, 16*SZ,  KQl, 0, 3*SZ,   nullptr, 0,
              Afp, (l < 2 ? As : nullptr), 16*SZ, cinv);
        if (l < 2) {
            mfire(As, SZ, 16*SZ,  Gs, SZ, 16*SZ,  G, 1,
                  Hf, Hs, 16*SZ, 1.f);
            mfire(Hs, SZ, 16*SZ,  As, SZ, 16*SZ,  Hf, 1,
                  G, Gs, 16*SZ, 1.f);
        }
    }
    // 16) rT1 = rT0 + A2^T[:,192:] * emb
    {
        Job js[1] = { mk(A2 + 192*320, SZ, 1, 320,  emb, 0, 128, 1,  rT1, RS, 128,
                         320, 128, 128, 1.f, 1, rT0, 0, 128, 0, 0) };
        int nb[1] = {160}; fire(js, nb, 1);
    }
    // 17) rT2 = rT1 + A1^T * rT1
    {
        Job js[1] = { mk(A1, SZ, 1, 320,  rT1, RS, 128, 1,  rT2, RS, 128,
                         320, 128, 320, 1.f, 1, rT1, RS, 128, 0, 0) };
        int nb[1] = {160}; fire(js, nb, 1);
    }
    // 18) rT3 = rT2 + A0^T * rT2
    {
        Job js[1] = { mk(A0, SZ, 1, 320,  rT2, RS, 128, 1,  rT3, RS, 128,
                         320, 128, 320, 1.f, 1, rT2, RS, 128, 0, 0) };
        int nb[1] = {160}; fire(js, nb, 1);
    }
    // 19) Mmid = E^T * rT3[64:192]
    {
        Job js[1] = { mk(emb, 0, 1, 128,  rT3 + 64*128, RS, 128, 1,  Mmid, 16384, 128,
                         128, 128, 128, 1.f, 0, 0, 0, 0, 0, 0) };
        int nb[1] = {64}; fire(js, nb, 1);
    }
    // 20) logits + softmax
    logits_sm_k<<<dim3(32, 16), 256, 0, stream>>>(x, rT3, Mmid, logits, pred);
}